// Round 7
// baseline (214.005 us; speedup 1.0000x reference)
//
#include <hip/hip_runtime.h>
#include <hip/hip_bf16.h>
#include <hip/hip_fp16.h>

// GCN forward: emb-gather -> GCNConv(64->128) -> ReLU -> GCNConv(128->128) -> ReLU
//              -> global_max_pool -> Linear(128->10)
// N=100000, E=600000, VOCAB=5000, G=2000, C=10.
// Layer-1 aggregation done in 64-dim embedding space (exact by linearity), then two
// no-LDS MFMA GEMMs. fp16 intermediates. Own k_zero kernel (rocclr fillBuffer is ~40us!).

typedef _Float16 h8 __attribute__((ext_vector_type(8)));
typedef float f32x4 __attribute__((ext_vector_type(4)));

// Zero deg (n4i int4s) and pool (p4i int4s). Grid-stride.
__global__ __launch_bounds__(256) void k_zero(int4* __restrict__ deg, int n4i,
                                              int4* __restrict__ pool, int p4i) {
    int t = blockIdx.x * 256 + threadIdx.x;
    int4 z = make_int4(0, 0, 0, 0);
    if (t < n4i) deg[t] = z;
    if (t < p4i) pool[t] = z;
}

// Fused: [0,gE) degree atomics; [gE,gE+nCast) e16 = fp16(emb); then W1T; then W2T.
__global__ __launch_bounds__(256) void k_degprep(const int* __restrict__ dst, int* __restrict__ deg, int E,
                                                 const float* __restrict__ emb, __half2* __restrict__ e16,
                                                 const float* __restrict__ W1, _Float16* __restrict__ W1T,
                                                 const float* __restrict__ W2, _Float16* __restrict__ W2T,
                                                 int nEmbF, int gE, int nCast) {
    int bid = blockIdx.x;
    if (bid < gE) {
        int e = bid * 256 + threadIdx.x;
        if (e < E) atomicAdd(&deg[dst[e]], 1);
    } else if (bid < gE + nCast) {
        int t = (bid - gE) * 256 + threadIdx.x;  // one thread = 4 floats
        if (t * 4 < nEmbF) {
            float4 v = *(const float4*)&emb[t * 4];
            e16[t * 2] = __floats2half2_rn(v.x, v.y);
            e16[t * 2 + 1] = __floats2half2_rn(v.z, v.w);
        }
    } else if (bid < gE + nCast + 32) {
        int t = (bid - gE - nCast) * 256 + threadIdx.x;  // 128*64
        int c = t >> 6, k = t & 63;
        W1T[c * 64 + k] = (_Float16)W1[k * 128 + c];
    } else {
        int t = (bid - gE - nCast - 32) * 256 + threadIdx.x;  // 128*128
        if (t < 128 * 128) {
            int c = t >> 7, k = t & 127;
            W2T[c * 128 + k] = (_Float16)W2[k * 128 + c];
        }
    }
}

// scan1 + dinv fused
__global__ __launch_bounds__(256) void k_scan1(const int* __restrict__ deg, int* __restrict__ exc,
                                               int* __restrict__ bsums, float* __restrict__ dinv, int N) {
    __shared__ int s[256];
    int i = blockIdx.x * 256 + threadIdx.x;
    int v = (i < N) ? deg[i] : 0;
    if (i < N) dinv[i] = rsqrtf((float)(v + 1));  // +1 self-loop
    s[threadIdx.x] = v;
    __syncthreads();
    for (int off = 1; off < 256; off <<= 1) {
        int t = (threadIdx.x >= (unsigned)off) ? s[threadIdx.x - off] : 0;
        __syncthreads();
        s[threadIdx.x] += t;
        __syncthreads();
    }
    if (i < N) exc[i] = s[threadIdx.x] - v;
    if (threadIdx.x == 255) bsums[blockIdx.x] = s[255];
}

__global__ __launch_bounds__(512) void k_scan2(int* __restrict__ bsums, int nb) {
    __shared__ int s[512];
    int i = threadIdx.x;
    int v = (i < nb) ? bsums[i] : 0;
    s[i] = v;
    __syncthreads();
    for (int off = 1; off < 512; off <<= 1) {
        int t = (i >= off) ? s[i - off] : 0;
        __syncthreads();
        s[i] += t;
        __syncthreads();
    }
    if (i < nb) bsums[i] = s[i] - v;
}

__global__ __launch_bounds__(256) void k_scan3(int* __restrict__ rowstart, int* __restrict__ cursor,
                                               const int* __restrict__ bsums, int N, int E) {
    int i = blockIdx.x * 256 + threadIdx.x;
    if (i < N) {
        int r = rowstart[i] + bsums[blockIdx.x];
        rowstart[i] = r;
        cursor[i] = r;
    }
    if (i == 0 && blockIdx.x == 0) rowstart[N] = E;
}

// CSR fill: ed[pos] = {x[src], dinv[src] bits}; cols[pos] = src
__global__ __launch_bounds__(256) void k_fill(const int* __restrict__ src, const int* __restrict__ dst,
                                              const int* __restrict__ x, const float* __restrict__ dinv,
                                              int* __restrict__ cursor, int2* __restrict__ ed,
                                              int* __restrict__ cols, int E) {
    int e = blockIdx.x * 256 + threadIdx.x;
    if (e < E) {
        int d = dst[e];
        int s = src[e];
        int pos = atomicAdd(&cursor[d], 1);
        ed[pos] = make_int2(x[s], __float_as_int(dinv[s]));
        cols[pos] = s;
    }
}

// 64-dim embedding-space aggregation: Xagg[i] = di*(di*e16[x_i] + sum_j dj*e16[x_j]), fp16.
// Half-wave per 2 nodes; dual 8-deep clamped gather batches (row = 32 lanes x half2).
__global__ __launch_bounds__(256) void k_agge(const __half2* __restrict__ e16, const int* __restrict__ x,
                                              const float* __restrict__ dinv, const int* __restrict__ rs,
                                              const int2* __restrict__ ed, __half2* __restrict__ Xagg, int N) {
    int lane = threadIdx.x & 31;
    int n0 = (blockIdx.x * 8 + (threadIdx.x >> 5)) * 2;
    if (n0 >= N) return;
    int nB = (n0 + 1 < N) ? n0 + 1 : n0;
    int cA0 = rs[n0], cA1 = rs[n0 + 1];
    int cB0 = rs[nB], cB1 = rs[nB + 1];
    bool hasA = cA0 < cA1, hasB = cB0 < cB1;
    __half2 tA[8], tB[8];
    float wA[8], wB[8];
    if (hasA) {
#pragma unroll
        for (int i = 0; i < 8; ++i) {
            int ei = cA0 + i;
            int ec = (ei < cA1) ? ei : cA1 - 1;
            int2 r = ed[ec];
            tA[i] = e16[(size_t)r.x * 32 + lane];
            wA[i] = (ei < cA1) ? __int_as_float(r.y) : 0.f;
        }
    }
    if (hasB) {
#pragma unroll
        for (int i = 0; i < 8; ++i) {
            int ei = cB0 + i;
            int ec = (ei < cB1) ? ei : cB1 - 1;
            int2 r = ed[ec];
            tB[i] = e16[(size_t)r.x * 32 + lane];
            wB[i] = (ei < cB1) ? __int_as_float(r.y) : 0.f;
        }
    }
    float dA = dinv[n0], dB = dinv[nB];
    float2 sA = __half22float2(e16[(size_t)x[n0] * 32 + lane]);
    float2 sB = __half22float2(e16[(size_t)x[nB] * 32 + lane]);
    float aA0 = dA * sA.x, aA1 = dA * sA.y;
    float aB0 = dB * sB.x, aB1 = dB * sB.y;
    if (hasA) {
#pragma unroll
        for (int i = 0; i < 8; ++i) {
            float2 tf = __half22float2(tA[i]);
            aA0 = fmaf(wA[i], tf.x, aA0);
            aA1 = fmaf(wA[i], tf.y, aA1);
        }
    }
    if (hasB) {
#pragma unroll
        for (int i = 0; i < 8; ++i) {
            float2 tf = __half22float2(tB[i]);
            aB0 = fmaf(wB[i], tf.x, aB0);
            aB1 = fmaf(wB[i], tf.y, aB1);
        }
    }
    for (int e = cA0 + 8; e < cA1; e += 8) {
#pragma unroll
        for (int i = 0; i < 8; ++i) {
            int ei = e + i;
            int ec = (ei < cA1) ? ei : cA1 - 1;
            int2 r = ed[ec];
            tA[i] = e16[(size_t)r.x * 32 + lane];
            wA[i] = (ei < cA1) ? __int_as_float(r.y) : 0.f;
        }
#pragma unroll
        for (int i = 0; i < 8; ++i) {
            float2 tf = __half22float2(tA[i]);
            aA0 = fmaf(wA[i], tf.x, aA0);
            aA1 = fmaf(wA[i], tf.y, aA1);
        }
    }
    for (int e = cB0 + 8; e < cB1; e += 8) {
#pragma unroll
        for (int i = 0; i < 8; ++i) {
            int ei = e + i;
            int ec = (ei < cB1) ? ei : cB1 - 1;
            int2 r = ed[ec];
            tB[i] = e16[(size_t)r.x * 32 + lane];
            wB[i] = (ei < cB1) ? __int_as_float(r.y) : 0.f;
        }
#pragma unroll
        for (int i = 0; i < 8; ++i) {
            float2 tf = __half22float2(tB[i]);
            aB0 = fmaf(wB[i], tf.x, aB0);
            aB1 = fmaf(wB[i], tf.y, aB1);
        }
    }
    Xagg[(size_t)n0 * 32 + lane] = __floats2half2_rn(dA * aA0, dA * aA1);
    Xagg[(size_t)nB * 32 + lane] = __floats2half2_rn(dB * aB0, dB * aB1);
}

// h1 = relu(Xagg @ W1 + b1): (N x 64)@(64 x 128). MFMA, wave = 16 rows. No LDS.
__global__ __launch_bounds__(256) void k_gemm1(const _Float16* __restrict__ A, const _Float16* __restrict__ W1T,
                                               const float* __restrict__ b1, _Float16* __restrict__ h1, int N) {
    int lane = threadIdx.x & 63;
    int wid = threadIdx.x >> 6;
    int r = lane & 15, kg = lane >> 4;
    int row0 = blockIdx.x * 64 + wid * 16;
    int arow = row0 + r;
    if (arow >= N) arow = N - 1;
    const _Float16* ab = A + (size_t)arow * 64 + kg * 8;
    const _Float16* bb = W1T + (size_t)r * 64 + kg * 8;
    f32x4 acc[8];
#pragma unroll
    for (int ct = 0; ct < 8; ++ct) acc[ct] = (f32x4){0.f, 0.f, 0.f, 0.f};
#pragma unroll
    for (int kc = 0; kc < 2; ++kc) {
        h8 a = *(const h8*)(ab + kc * 32);
#pragma unroll
        for (int ct = 0; ct < 8; ++ct) {
            h8 b = *(const h8*)(bb + kc * 32 + ct * 1024);
            acc[ct] = __builtin_amdgcn_mfma_f32_16x16x32_f16(a, b, acc[ct], 0, 0, 0);
        }
    }
#pragma unroll
    for (int ct = 0; ct < 8; ++ct) {
        float bias = b1[ct * 16 + r];
#pragma unroll
        for (int i = 0; i < 4; ++i) {
            int gr = row0 + 4 * kg + i;
            if (gr < N)
                h1[(size_t)gr * 128 + ct * 16 + r] = (_Float16)fmaxf(acc[ct][i] + bias, 0.f);
        }
    }
}

// P = dinv[i] * (h1 @ W2), fp16 out. MFMA, wave = 16 rows x 128 cols. No LDS.
__global__ __launch_bounds__(256) void k_gemm2(const _Float16* __restrict__ A, const _Float16* __restrict__ W2T,
                                               const float* __restrict__ dinv, _Float16* __restrict__ P, int N) {
    int lane = threadIdx.x & 63;
    int wid = threadIdx.x >> 6;
    int r = lane & 15, kg = lane >> 4;
    int row0 = blockIdx.x * 64 + wid * 16;
    int arow = row0 + r;
    if (arow >= N) arow = N - 1;
    const _Float16* ab = A + (size_t)arow * 128 + kg * 8;
    const _Float16* bb = W2T + (size_t)r * 128 + kg * 8;
    f32x4 acc[8];
#pragma unroll
    for (int ct = 0; ct < 8; ++ct) acc[ct] = (f32x4){0.f, 0.f, 0.f, 0.f};
#pragma unroll
    for (int kc = 0; kc < 4; ++kc) {
        h8 a = *(const h8*)(ab + kc * 32);
#pragma unroll
        for (int ct = 0; ct < 8; ++ct) {
            h8 b = *(const h8*)(bb + kc * 32 + ct * 2048);
            acc[ct] = __builtin_amdgcn_mfma_f32_16x16x32_f16(a, b, acc[ct], 0, 0, 0);
        }
    }
    float dv[4];
#pragma unroll
    for (int i = 0; i < 4; ++i) {
        int gr = row0 + 4 * kg + i;
        dv[i] = (gr < N) ? dinv[gr] : 0.f;
    }
#pragma unroll
    for (int ct = 0; ct < 8; ++ct) {
#pragma unroll
        for (int i = 0; i < 4; ++i) {
            int gr = row0 + 4 * kg + i;
            if (gr < N) P[(size_t)gr * 128 + ct * 16 + r] = (_Float16)(acc[ct][i] * dv[i]);
        }
    }
}

typedef _Float16 h4v __attribute__((ext_vector_type(4)));

// Layer-2 + global_max_pool. 512-thr block = 16 half-waves x 2 nodes = 32 sorted nodes.
// Per-node z -> LDS graph slots (bank-rotated atomicMax) -> one global emit per (block,graph,feat).
__global__ __launch_bounds__(512) void k_agg2pool(const h4v* __restrict__ P4, const int* __restrict__ batch,
                                                  const float* __restrict__ dinv, const int* __restrict__ rs,
                                                  const int* __restrict__ cols, const float4* __restrict__ bias4,
                                                  float* __restrict__ pool, int N, int G) {
    __shared__ int lpool[4][128];
    int tid = threadIdx.x;
    lpool[tid >> 7][tid & 127] = 0;
    __syncthreads();
    int lane = tid & 31;
    int blk_n0 = blockIdx.x * 32;
    int gfirst = batch[(blk_n0 < N) ? blk_n0 : (N - 1)];
    int n0 = blk_n0 + (tid >> 5) * 2;
    if (n0 < N) {
        int nB = (n0 + 1 < N) ? n0 + 1 : n0;
        int cA0 = rs[n0], cA1 = rs[n0 + 1];
        int cB0 = rs[nB], cB1 = rs[nB + 1];
        bool hasA = cA0 < cA1, hasB = cB0 < cB1;
        h4v tA[8], tB[8];
        float wA[8], wB[8];
        if (hasA) {
#pragma unroll
            for (int i = 0; i < 8; ++i) {
                int ei = cA0 + i;
                int ec = (ei < cA1) ? ei : cA1 - 1;
                tA[i] = P4[(size_t)cols[ec] * 32 + lane];
                wA[i] = (ei < cA1) ? 1.f : 0.f;
            }
        }
        if (hasB) {
#pragma unroll
            for (int i = 0; i < 8; ++i) {
                int ei = cB0 + i;
                int ec = (ei < cB1) ? ei : cB1 - 1;
                tB[i] = P4[(size_t)cols[ec] * 32 + lane];
                wB[i] = (ei < cB1) ? 1.f : 0.f;
            }
        }
        h4v sA = P4[(size_t)n0 * 32 + lane];
        h4v sB = P4[(size_t)nB * 32 + lane];
        float aA[4], aB[4];
#pragma unroll
        for (int f = 0; f < 4; ++f) {
            aA[f] = (float)sA[f];
            aB[f] = (float)sB[f];
        }
        if (hasA) {
#pragma unroll
            for (int i = 0; i < 8; ++i)
#pragma unroll
                for (int f = 0; f < 4; ++f) aA[f] = fmaf(wA[i], (float)tA[i][f], aA[f]);
        }
        if (hasB) {
#pragma unroll
            for (int i = 0; i < 8; ++i)
#pragma unroll
                for (int f = 0; f < 4; ++f) aB[f] = fmaf(wB[i], (float)tB[i][f], aB[f]);
        }
        for (int e = cA0 + 8; e < cA1; e += 8) {
#pragma unroll
            for (int i = 0; i < 8; ++i) {
                int ei = e + i;
                int ec = (ei < cA1) ? ei : cA1 - 1;
                tA[i] = P4[(size_t)cols[ec] * 32 + lane];
                wA[i] = (ei < cA1) ? 1.f : 0.f;
            }
#pragma unroll
            for (int i = 0; i < 8; ++i)
#pragma unroll
                for (int f = 0; f < 4; ++f) aA[f] = fmaf(wA[i], (float)tA[i][f], aA[f]);
        }
        for (int e = cB0 + 8; e < cB1; e += 8) {
#pragma unroll
            for (int i = 0; i < 8; ++i) {
                int ei = e + i;
                int ec = (ei < cB1) ? ei : cB1 - 1;
                tB[i] = P4[(size_t)cols[ec] * 32 + lane];
                wB[i] = (ei < cB1) ? 1.f : 0.f;
            }
#pragma unroll
            for (int i = 0; i < 8; ++i)
#pragma unroll
                for (int f = 0; f < 4; ++f) aB[f] = fmaf(wB[i], (float)tB[i][f], aB[f]);
        }
        float dA = dinv[n0], dB = dinv[nB];
        int gA = batch[n0], gB = batch[nB];
        float4 b = bias4[lane];
        float bv[4] = {b.x, b.y, b.z, b.w};
        float zA[4], zB[4];
#pragma unroll
        for (int f = 0; f < 4; ++f) {
            zA[f] = fmaxf(fmaf(dA, aA[f], bv[f]), 0.f);
            zB[f] = fmaxf(fmaf(dB, aB[f], bv[f]), 0.f);
        }
        int rot = (lane >> 3) & 3;  // bank-rotation: 32 lanes hit 32 distinct banks per step
        auto emit = [&](int g, const float* m) {
            int slot = g - gfirst;
            if (slot < 4) {
#pragma unroll
                for (int f = 0; f < 4; ++f) {
                    int ff = (f + rot) & 3;
                    if (m[ff] > 0.f) atomicMax(&lpool[slot][lane * 4 + ff], __float_as_int(m[ff]));
                }
            } else {
                float* pg = pool + (size_t)g * 128 + lane * 4;
#pragma unroll
                for (int f = 0; f < 4; ++f)
                    if (m[f] > 0.f) atomicMax((int*)(pg + f), __float_as_int(m[f]));
            }
        };
        if (gA == gB) {
            float m[4];
#pragma unroll
            for (int f = 0; f < 4; ++f) m[f] = fmaxf(zA[f], zB[f]);
            emit(gA, m);
        } else {
            emit(gA, zA);
            emit(gB, zB);
        }
    }
    __syncthreads();
    int s = tid >> 7, f = tid & 127;
    int v = lpool[s][f];
    if (v > 0) atomicMax((int*)&pool[(size_t)(gfirst + s) * 128 + f], v);
}

// out[g][c] = blin[c] + sum_f pool[g][f] * Wlin[f][c]
__global__ __launch_bounds__(256) void k_final(const float* __restrict__ pool, const float* __restrict__ Wlin,
                                               const float* __restrict__ blin, float* __restrict__ out, int G) {
    int t = blockIdx.x * 256 + threadIdx.x;
    if (t >= G * 10) return;
    int g = t / 10, c = t % 10;
    float acc = blin[c];
    const float* pr = pool + (size_t)g * 128;
#pragma unroll 8
    for (int f = 0; f < 128; ++f) acc = fmaf(pr[f], Wlin[f * 10 + c], acc);
    out[t] = acc;
}

extern "C" void kernel_launch(void* const* d_in, const int* in_sizes, int n_in,
                              void* d_out, int out_size, void* d_ws, size_t ws_size,
                              hipStream_t stream) {
    const int* x = (const int*)d_in[0];
    const int* ei = (const int*)d_in[1];
    const int* batch = (const int*)d_in[2];
    const float* emb = (const float*)d_in[4];
    const float* W1 = (const float*)d_in[5];
    const float* b1 = (const float*)d_in[6];
    const float* W2 = (const float*)d_in[7];
    const float* b2 = (const float*)d_in[8];
    const float* Wlin = (const float*)d_in[9];
    const float* blin = (const float*)d_in[10];
    float* out = (float*)d_out;

    int N = in_sizes[0];
    int E = in_sizes[1] / 2;
    int VOCAB = in_sizes[4] / 64;
    int G = out_size / 10;
    const int* srcp = ei;
    const int* dstp = ei + E;

    char* p = (char*)d_ws;
    auto alloc = [&](size_t bytes) -> char* {
        char* r = p;
        p += (bytes + 255) & ~(size_t)255;
        return r;
    };
    int* deg = (int*)alloc((size_t)N * 4);
    int* cursor = (int*)alloc((size_t)N * 4);
    int* rowstart = (int*)alloc((size_t)(N + 1) * 4);
    int* bsums = (int*)alloc(512 * 4);
    float* dinv = (float*)alloc((size_t)N * 4);
    int2* ed = (int2*)alloc((size_t)E * 8);
    int* cols = (int*)alloc((size_t)E * 4);
    _Float16* e16 = (_Float16*)alloc((size_t)VOCAB * 64 * 2);
    _Float16* W1T = (_Float16*)alloc(128 * 64 * 2);
    _Float16* W2T = (_Float16*)alloc(128 * 128 * 2);
    _Float16* Xagg = (_Float16*)alloc((size_t)N * 64 * 2);
    _Float16* h1 = (_Float16*)alloc((size_t)N * 128 * 2);
    _Float16* P = (_Float16*)alloc((size_t)N * 128 * 2);
    float* pool = (float*)alloc((size_t)G * 128 * 4);

    int gE = (E + 255) / 256;
    int gN = (N + 255) / 256;  // 391 <= 512 (scan2 capacity)
    int nEmbF = VOCAB * 64;
    int nCast = (nEmbF / 4 + 255) / 256;

    int n4i = N / 4, p4i = G * 128 / 4;
    int zg = ((n4i > p4i ? n4i : p4i) + 255) / 256;
    k_zero<<<zg, 256, 0, stream>>>((int4*)deg, n4i, (int4*)pool, p4i);
    k_degprep<<<gE + nCast + 32 + 64, 256, 0, stream>>>(dstp, deg, E, emb, (__half2*)e16, W1, W1T,
                                                        W2, W2T, nEmbF, gE, nCast);
    k_scan1<<<gN, 256, 0, stream>>>(deg, rowstart, bsums, dinv, N);
    k_scan2<<<1, 512, 0, stream>>>(bsums, gN);
    k_scan3<<<gN, 256, 0, stream>>>(rowstart, cursor, bsums, N, E);
    k_fill<<<gE, 256, 0, stream>>>(srcp, dstp, x, dinv, cursor, ed, cols, E);
    // agge: 256-thr block = 8 half-waves x 2 nodes = 16 nodes
    k_agge<<<(N + 15) / 16, 256, 0, stream>>>((const __half2*)e16, x, dinv, rowstart, ed,
                                              (__half2*)Xagg, N);
    k_gemm1<<<(N + 63) / 64, 256, 0, stream>>>(Xagg, W1T, b1, h1, N);
    k_gemm2<<<(N + 63) / 64, 256, 0, stream>>>(h1, W2T, dinv, P, N);
    // agg2pool: 512-thr block = 16 half-waves x 2 nodes = 32 nodes
    k_agg2pool<<<(N + 31) / 32, 512, 0, stream>>>((const h4v*)P, batch, dinv, rowstart, cols,
                                                  (const float4*)b2, pool, N, G);
    k_final<<<(G * 10 + 255) / 256, 256, 0, stream>>>(pool, Wlin, blin, out, G);
}

// Round 8
// 196.508 us; speedup vs baseline: 1.0890x; 1.0890x over previous
//
#include <hip/hip_runtime.h>
#include <hip/hip_bf16.h>
#include <hip/hip_fp16.h>

// GCN forward: emb-gather -> GCNConv(64->128) -> ReLU -> GCNConv(128->128) -> ReLU
//              -> global_max_pool -> Linear(128->10)
// N=100000, E=600000, VOCAB=5000, G=2000, C=10.
// k_mlp fuses: 64-dim embedding-space aggregation (exact by linearity) -> LDS ->
// MFMA gemm1(+bias,relu) -> LDS -> MFMA gemm2(dinv scale) -> P. fp16 intermediates.
// k_agg2pool: 16-deep dual-interleaved gathers, LDS pool consolidation.

typedef _Float16 h8 __attribute__((ext_vector_type(8)));
typedef _Float16 h4v __attribute__((ext_vector_type(4)));
typedef float f32x4 __attribute__((ext_vector_type(4)));

// Zero deg (n4i int4s) and pool (p4i int4s).
__global__ __launch_bounds__(256) void k_zero(int4* __restrict__ deg, int n4i,
                                              int4* __restrict__ pool, int p4i) {
    int t = blockIdx.x * 256 + threadIdx.x;
    int4 z = make_int4(0, 0, 0, 0);
    if (t < n4i) deg[t] = z;
    if (t < p4i) pool[t] = z;
}

// Fused: [0,gE) degree atomics; [gE,gE+nCast) e16 = fp16(emb); then W1T; then W2T.
__global__ __launch_bounds__(256) void k_degprep(const int* __restrict__ dst, int* __restrict__ deg, int E,
                                                 const float* __restrict__ emb, __half2* __restrict__ e16,
                                                 const float* __restrict__ W1, _Float16* __restrict__ W1T,
                                                 const float* __restrict__ W2, _Float16* __restrict__ W2T,
                                                 int nEmbF, int gE, int nCast) {
    int bid = blockIdx.x;
    if (bid < gE) {
        int e = bid * 256 + threadIdx.x;
        if (e < E) atomicAdd(&deg[dst[e]], 1);
    } else if (bid < gE + nCast) {
        int t = (bid - gE) * 256 + threadIdx.x;  // one thread = 4 floats
        if (t * 4 < nEmbF) {
            float4 v = *(const float4*)&emb[t * 4];
            e16[t * 2] = __floats2half2_rn(v.x, v.y);
            e16[t * 2 + 1] = __floats2half2_rn(v.z, v.w);
        }
    } else if (bid < gE + nCast + 32) {
        int t = (bid - gE - nCast) * 256 + threadIdx.x;  // 128*64
        int c = t >> 6, k = t & 63;
        W1T[c * 64 + k] = (_Float16)W1[k * 128 + c];
    } else {
        int t = (bid - gE - nCast - 32) * 256 + threadIdx.x;  // 128*128
        if (t < 128 * 128) {
            int c = t >> 7, k = t & 127;
            W2T[c * 128 + k] = (_Float16)W2[k * 128 + c];
        }
    }
}

// scan1 + dinv fused
__global__ __launch_bounds__(256) void k_scan1(const int* __restrict__ deg, int* __restrict__ exc,
                                               int* __restrict__ bsums, float* __restrict__ dinv, int N) {
    __shared__ int s[256];
    int i = blockIdx.x * 256 + threadIdx.x;
    int v = (i < N) ? deg[i] : 0;
    if (i < N) dinv[i] = rsqrtf((float)(v + 1));  // +1 self-loop
    s[threadIdx.x] = v;
    __syncthreads();
    for (int off = 1; off < 256; off <<= 1) {
        int t = (threadIdx.x >= (unsigned)off) ? s[threadIdx.x - off] : 0;
        __syncthreads();
        s[threadIdx.x] += t;
        __syncthreads();
    }
    if (i < N) exc[i] = s[threadIdx.x] - v;
    if (threadIdx.x == 255) bsums[blockIdx.x] = s[255];
}

__global__ __launch_bounds__(512) void k_scan2(int* __restrict__ bsums, int nb) {
    __shared__ int s[512];
    int i = threadIdx.x;
    int v = (i < nb) ? bsums[i] : 0;
    s[i] = v;
    __syncthreads();
    for (int off = 1; off < 512; off <<= 1) {
        int t = (i >= off) ? s[i - off] : 0;
        __syncthreads();
        s[i] += t;
        __syncthreads();
    }
    if (i < nb) bsums[i] = s[i] - v;
}

__global__ __launch_bounds__(256) void k_scan3(int* __restrict__ rowstart, int* __restrict__ cursor,
                                               const int* __restrict__ bsums, int N, int E) {
    int i = blockIdx.x * 256 + threadIdx.x;
    if (i < N) {
        int r = rowstart[i] + bsums[blockIdx.x];
        rowstart[i] = r;
        cursor[i] = r;
    }
    if (i == 0 && blockIdx.x == 0) rowstart[N] = E;
}

// CSR fill: ed[pos] = {x[src], dinv[src] bits}; cols[pos] = src
__global__ __launch_bounds__(256) void k_fill(const int* __restrict__ src, const int* __restrict__ dst,
                                              const int* __restrict__ x, const float* __restrict__ dinv,
                                              int* __restrict__ cursor, int2* __restrict__ ed,
                                              int* __restrict__ cols, int E) {
    int e = blockIdx.x * 256 + threadIdx.x;
    if (e < E) {
        int d = dst[e];
        int s = src[e];
        int pos = atomicAdd(&cursor[d], 1);
        ed[pos] = make_int2(x[s], __float_as_int(dinv[s]));
        cols[pos] = s;
    }
}

// Fused node pipeline: block = 64 nodes.
// Phase 1: Xs[nl] = di*(di*e16[x_i] + sum_j dj*e16[x_j])  (8 half-waves x 8 nodes)
// Phase 2: Hs = relu(Xs @ W1 + b1)   (4 waves x 16 rows, MFMA)
// Phase 3: P  = dinv * (Hs @ W2)     (MFMA)
__global__ __launch_bounds__(256) void k_mlp(const __half2* __restrict__ e16, const int* __restrict__ x,
                                             const float* __restrict__ dinv, const int* __restrict__ rs,
                                             const int2* __restrict__ ed, const _Float16* __restrict__ W1T,
                                             const float* __restrict__ b1, const _Float16* __restrict__ W2T,
                                             _Float16* __restrict__ P, int N) {
    __shared__ _Float16 Xs[64][72];    // 64-dim rows, stride 72 (144B: 16B-aligned, bank-spread)
    __shared__ _Float16 Hs[64][136];   // 128-dim rows, stride 136 (272B: 16B-aligned, bank-spread)
    int tid = threadIdx.x;
    int blk0 = blockIdx.x * 64;
    // ---- Phase 1: embedding-space aggregation ----
    {
        int lane = tid & 31;
        int hw = tid >> 5;
        for (int pass = 0; pass < 4; ++pass) {
            int nl = hw * 8 + pass * 2;
            int gA = blk0 + nl;     if (gA >= N) gA = N - 1;
            int gB = blk0 + nl + 1; if (gB >= N) gB = N - 1;
            int cA0 = rs[gA], cA1 = rs[gA + 1];
            int cB0 = rs[gB], cB1 = rs[gB + 1];
            bool hasA = cA0 < cA1, hasB = cB0 < cB1;
            __half2 tA[8], tB[8];
            float wA[8], wB[8];
#pragma unroll
            for (int i = 0; i < 8; ++i) {
                int ei = cA0 + i;
                int ec = (ei < cA1) ? ei : (hasA ? cA1 - 1 : 0);
                int2 r2 = ed[ec];
                tA[i] = e16[(size_t)r2.x * 32 + lane];
                wA[i] = (ei < cA1) ? __int_as_float(r2.y) : 0.f;
            }
#pragma unroll
            for (int i = 0; i < 8; ++i) {
                int ei = cB0 + i;
                int ec = (ei < cB1) ? ei : (hasB ? cB1 - 1 : 0);
                int2 r2 = ed[ec];
                tB[i] = e16[(size_t)r2.x * 32 + lane];
                wB[i] = (ei < cB1) ? __int_as_float(r2.y) : 0.f;
            }
            float dA = dinv[gA], dB = dinv[gB];
            float2 sA = __half22float2(e16[(size_t)x[gA] * 32 + lane]);
            float2 sB = __half22float2(e16[(size_t)x[gB] * 32 + lane]);
            float aA0 = dA * sA.x, aA1 = dA * sA.y;
            float aB0 = dB * sB.x, aB1 = dB * sB.y;
#pragma unroll
            for (int i = 0; i < 8; ++i) {
                float2 tf = __half22float2(tA[i]);
                aA0 = fmaf(wA[i], tf.x, aA0);
                aA1 = fmaf(wA[i], tf.y, aA1);
            }
#pragma unroll
            for (int i = 0; i < 8; ++i) {
                float2 tf = __half22float2(tB[i]);
                aB0 = fmaf(wB[i], tf.x, aB0);
                aB1 = fmaf(wB[i], tf.y, aB1);
            }
            for (int e = cA0 + 8; e < cA1; e += 8) {
#pragma unroll
                for (int i = 0; i < 8; ++i) {
                    int ei = e + i;
                    int ec = (ei < cA1) ? ei : cA1 - 1;
                    int2 r2 = ed[ec];
                    tA[i] = e16[(size_t)r2.x * 32 + lane];
                    wA[i] = (ei < cA1) ? __int_as_float(r2.y) : 0.f;
                }
#pragma unroll
                for (int i = 0; i < 8; ++i) {
                    float2 tf = __half22float2(tA[i]);
                    aA0 = fmaf(wA[i], tf.x, aA0);
                    aA1 = fmaf(wA[i], tf.y, aA1);
                }
            }
            for (int e = cB0 + 8; e < cB1; e += 8) {
#pragma unroll
                for (int i = 0; i < 8; ++i) {
                    int ei = e + i;
                    int ec = (ei < cB1) ? ei : cB1 - 1;
                    int2 r2 = ed[ec];
                    tB[i] = e16[(size_t)r2.x * 32 + lane];
                    wB[i] = (ei < cB1) ? __int_as_float(r2.y) : 0.f;
                }
#pragma unroll
                for (int i = 0; i < 8; ++i) {
                    float2 tf = __half22float2(tB[i]);
                    aB0 = fmaf(wB[i], tf.x, aB0);
                    aB1 = fmaf(wB[i], tf.y, aB1);
                }
            }
            *(__half2*)&Xs[nl][lane * 2] = __floats2half2_rn(dA * aA0, dA * aA1);
            *(__half2*)&Xs[nl + 1][lane * 2] = __floats2half2_rn(dB * aB0, dB * aB1);
        }
    }
    __syncthreads();
    int l = tid & 63, wid = tid >> 6;
    int r = l & 15, kg = l >> 4;
    // ---- Phase 2: Hs = relu(Xs @ W1 + b1) ----
    {
        f32x4 acc[8];
#pragma unroll
        for (int ct = 0; ct < 8; ++ct) acc[ct] = (f32x4){0.f, 0.f, 0.f, 0.f};
#pragma unroll
        for (int kc = 0; kc < 2; ++kc) {
            h8 a = *(const h8*)&Xs[wid * 16 + r][kc * 32 + kg * 8];
#pragma unroll
            for (int ct = 0; ct < 8; ++ct) {
                h8 b = *(const h8*)(W1T + (size_t)r * 64 + kg * 8 + kc * 32 + ct * 1024);
                acc[ct] = __builtin_amdgcn_mfma_f32_16x16x32_f16(a, b, acc[ct], 0, 0, 0);
            }
        }
#pragma unroll
        for (int ct = 0; ct < 8; ++ct) {
            float bias = b1[ct * 16 + r];
#pragma unroll
            for (int i = 0; i < 4; ++i)
                Hs[wid * 16 + 4 * kg + i][ct * 16 + r] = (_Float16)fmaxf(acc[ct][i] + bias, 0.f);
        }
    }
    __syncthreads();
    // ---- Phase 3: P = dinv * (Hs @ W2) ----
    {
        f32x4 acc[8];
#pragma unroll
        for (int ct = 0; ct < 8; ++ct) acc[ct] = (f32x4){0.f, 0.f, 0.f, 0.f};
#pragma unroll
        for (int kc = 0; kc < 4; ++kc) {
            h8 a = *(const h8*)&Hs[wid * 16 + r][kc * 32 + kg * 8];
#pragma unroll
            for (int ct = 0; ct < 8; ++ct) {
                h8 b = *(const h8*)(W2T + (size_t)r * 128 + kg * 8 + kc * 32 + ct * 2048);
                acc[ct] = __builtin_amdgcn_mfma_f32_16x16x32_f16(a, b, acc[ct], 0, 0, 0);
            }
        }
        float dv[4];
#pragma unroll
        for (int i = 0; i < 4; ++i) {
            int gr = blk0 + wid * 16 + 4 * kg + i;
            dv[i] = (gr < N) ? dinv[gr] : 0.f;
        }
#pragma unroll
        for (int ct = 0; ct < 8; ++ct) {
#pragma unroll
            for (int i = 0; i < 4; ++i) {
                int gr = blk0 + wid * 16 + 4 * kg + i;
                if (gr < N) P[(size_t)gr * 128 + ct * 16 + r] = (_Float16)(acc[ct][i] * dv[i]);
            }
        }
    }
}

// Layer-2 + global_max_pool. 256-thr block = 8 half-waves x 2 nodes = 16 sorted nodes.
// 16-deep dual-interleaved clamped gathers (32 rows in flight). LDS pool slots, one
// global emit per (block, graph, feature).
__global__ __launch_bounds__(256) void k_agg2pool(const h4v* __restrict__ P4, const int* __restrict__ batch,
                                                  const float* __restrict__ dinv, const int* __restrict__ rs,
                                                  const int* __restrict__ cols, const float4* __restrict__ bias4,
                                                  float* __restrict__ pool, int N, int G) {
    __shared__ int lpool[4][128];
    int tid = threadIdx.x;
    lpool[tid >> 7][tid & 127] = 0;
    lpool[(tid >> 7) + 2][tid & 127] = 0;
    __syncthreads();
    int lane = tid & 31;
    int blk_n0 = blockIdx.x * 16;
    int gfirst = batch[(blk_n0 < N) ? blk_n0 : (N - 1)];
    int n0 = blk_n0 + (tid >> 5) * 2;
    if (n0 < N) {
        int nA = n0;
        int nB = (n0 + 1 < N) ? n0 + 1 : n0;
        int cA0 = rs[nA], cA1 = rs[nA + 1];
        int cB0 = rs[nB], cB1 = rs[nB + 1];
        bool hasA = cA0 < cA1, hasB = cB0 < cB1;
        h4v sA = P4[(size_t)nA * 32 + lane];
        h4v sB = P4[(size_t)nB * 32 + lane];
        float aA[4], aB[4];
#pragma unroll
        for (int f = 0; f < 4; ++f) {
            aA[f] = (float)sA[f];
            aB[f] = (float)sB[f];
        }
        {
            h4v tA[16], tB[16];
#pragma unroll
            for (int i = 0; i < 16; ++i) {
                int ei = cA0 + i;
                int ec = (ei < cA1) ? ei : (hasA ? cA1 - 1 : 0);
                tA[i] = P4[(size_t)cols[ec] * 32 + lane];
            }
#pragma unroll
            for (int i = 0; i < 16; ++i) {
                int ei = cB0 + i;
                int ec = (ei < cB1) ? ei : (hasB ? cB1 - 1 : 0);
                tB[i] = P4[(size_t)cols[ec] * 32 + lane];
            }
#pragma unroll
            for (int i = 0; i < 16; ++i) {
                float w = (cA0 + i < cA1) ? 1.f : 0.f;
#pragma unroll
                for (int f = 0; f < 4; ++f) aA[f] = fmaf(w, (float)tA[i][f], aA[f]);
            }
#pragma unroll
            for (int i = 0; i < 16; ++i) {
                float w = (cB0 + i < cB1) ? 1.f : 0.f;
#pragma unroll
                for (int f = 0; f < 4; ++f) aB[f] = fmaf(w, (float)tB[i][f], aB[f]);
            }
        }
        for (int e = cA0 + 16; e < cA1; e += 16) {
            h4v t[16];
#pragma unroll
            for (int i = 0; i < 16; ++i) {
                int ei = e + i;
                int ec = (ei < cA1) ? ei : cA1 - 1;
                t[i] = P4[(size_t)cols[ec] * 32 + lane];
            }
#pragma unroll
            for (int i = 0; i < 16; ++i) {
                float w = (e + i < cA1) ? 1.f : 0.f;
#pragma unroll
                for (int f = 0; f < 4; ++f) aA[f] = fmaf(w, (float)t[i][f], aA[f]);
            }
        }
        for (int e = cB0 + 16; e < cB1; e += 16) {
            h4v t[16];
#pragma unroll
            for (int i = 0; i < 16; ++i) {
                int ei = e + i;
                int ec = (ei < cB1) ? ei : cB1 - 1;
                t[i] = P4[(size_t)cols[ec] * 32 + lane];
            }
#pragma unroll
            for (int i = 0; i < 16; ++i) {
                float w = (e + i < cB1) ? 1.f : 0.f;
#pragma unroll
                for (int f = 0; f < 4; ++f) aB[f] = fmaf(w, (float)t[i][f], aB[f]);
            }
        }
        float dA = dinv[nA], dB = dinv[nB];
        int gA = batch[nA], gB = batch[nB];
        float4 b = bias4[lane];
        float bv[4] = {b.x, b.y, b.z, b.w};
        float zA[4], zB[4];
#pragma unroll
        for (int f = 0; f < 4; ++f) {
            zA[f] = fmaxf(fmaf(dA, aA[f], bv[f]), 0.f);
            zB[f] = fmaxf(fmaf(dB, aB[f], bv[f]), 0.f);
        }
        int rot = (lane >> 3) & 3;  // bank-rotation for LDS atomics
        auto emit = [&](int g, const float* m) {
            int slot = g - gfirst;
            if (slot < 4) {
#pragma unroll
                for (int f = 0; f < 4; ++f) {
                    int ff = (f + rot) & 3;
                    if (m[ff] > 0.f) atomicMax(&lpool[slot][lane * 4 + ff], __float_as_int(m[ff]));
                }
            } else {
                float* pg = pool + (size_t)g * 128 + lane * 4;
#pragma unroll
                for (int f = 0; f < 4; ++f)
                    if (m[f] > 0.f) atomicMax((int*)(pg + f), __float_as_int(m[f]));
            }
        };
        if (gA == gB) {
            float m[4];
#pragma unroll
            for (int f = 0; f < 4; ++f) m[f] = fmaxf(zA[f], zB[f]);
            emit(gA, m);
        } else {
            emit(gA, zA);
            emit(gB, zB);
        }
    }
    __syncthreads();
    {
        int f = tid & 127;
        for (int s = tid >> 7; s < 4; s += 2) {
            int v = lpool[s][f];
            if (v > 0) atomicMax((int*)&pool[(size_t)(gfirst + s) * 128 + f], v);
        }
    }
}

// out[g][c] = blin[c] + sum_f pool[g][f] * Wlin[f][c]
__global__ __launch_bounds__(256) void k_final(const float* __restrict__ pool, const float* __restrict__ Wlin,
                                               const float* __restrict__ blin, float* __restrict__ out, int G) {
    int t = blockIdx.x * 256 + threadIdx.x;
    if (t >= G * 10) return;
    int g = t / 10, c = t % 10;
    float acc = blin[c];
    const float* pr = pool + (size_t)g * 128;
#pragma unroll 8
    for (int f = 0; f < 128; ++f) acc = fmaf(pr[f], Wlin[f * 10 + c], acc);
    out[t] = acc;
}

extern "C" void kernel_launch(void* const* d_in, const int* in_sizes, int n_in,
                              void* d_out, int out_size, void* d_ws, size_t ws_size,
                              hipStream_t stream) {
    const int* x = (const int*)d_in[0];
    const int* ei = (const int*)d_in[1];
    const int* batch = (const int*)d_in[2];
    const float* emb = (const float*)d_in[4];
    const float* W1 = (const float*)d_in[5];
    const float* b1 = (const float*)d_in[6];
    const float* W2 = (const float*)d_in[7];
    const float* b2 = (const float*)d_in[8];
    const float* Wlin = (const float*)d_in[9];
    const float* blin = (const float*)d_in[10];
    float* out = (float*)d_out;

    int N = in_sizes[0];
    int E = in_sizes[1] / 2;
    int VOCAB = in_sizes[4] / 64;
    int G = out_size / 10;
    const int* srcp = ei;
    const int* dstp = ei + E;

    char* p = (char*)d_ws;
    auto alloc = [&](size_t bytes) -> char* {
        char* r = p;
        p += (bytes + 255) & ~(size_t)255;
        return r;
    };
    int* deg = (int*)alloc((size_t)N * 4);
    int* cursor = (int*)alloc((size_t)N * 4);
    int* rowstart = (int*)alloc((size_t)(N + 1) * 4);
    int* bsums = (int*)alloc(512 * 4);
    float* dinv = (float*)alloc((size_t)N * 4);
    int2* ed = (int2*)alloc((size_t)E * 8);
    int* cols = (int*)alloc((size_t)E * 4);
    _Float16* e16 = (_Float16*)alloc((size_t)VOCAB * 64 * 2);
    _Float16* W1T = (_Float16*)alloc(128 * 64 * 2);
    _Float16* W2T = (_Float16*)alloc(128 * 128 * 2);
    _Float16* P = (_Float16*)alloc((size_t)N * 128 * 2);
    float* pool = (float*)alloc((size_t)G * 128 * 4);

    int gE = (E + 255) / 256;
    int gN = (N + 255) / 256;  // 391 <= 512 (scan2 capacity)
    int nEmbF = VOCAB * 64;
    int nCast = (nEmbF / 4 + 255) / 256;

    int n4i = N / 4, p4i = G * 128 / 4;
    int zg = ((n4i > p4i ? n4i : p4i) + 255) / 256;
    k_zero<<<zg, 256, 0, stream>>>((int4*)deg, n4i, (int4*)pool, p4i);
    k_degprep<<<gE + nCast + 32 + 64, 256, 0, stream>>>(dstp, deg, E, emb, (__half2*)e16, W1, W1T,
                                                        W2, W2T, nEmbF, gE, nCast);
    k_scan1<<<gN, 256, 0, stream>>>(deg, rowstart, bsums, dinv, N);
    k_scan2<<<1, 512, 0, stream>>>(bsums, gN);
    k_scan3<<<gN, 256, 0, stream>>>(rowstart, cursor, bsums, N, E);
    k_fill<<<gE, 256, 0, stream>>>(srcp, dstp, x, dinv, cursor, ed, cols, E);
    k_mlp<<<(N + 63) / 64, 256, 0, stream>>>((const __half2*)e16, x, dinv, rowstart, ed, W1T, b1,
                                             W2T, P, N);
    k_agg2pool<<<(N + 15) / 16, 256, 0, stream>>>((const h4v*)P, batch, dinv, rowstart, cols,
                                                  (const float4*)b2, pool, N, G);
    k_final<<<(G * 10 + 255) / 256, 256, 0, stream>>>(pool, Wlin, blin, out, G);
}

// Round 9
// 195.423 us; speedup vs baseline: 1.0951x; 1.0056x over previous
//
#include <hip/hip_runtime.h>
#include <hip/hip_bf16.h>
#include <hip/hip_fp16.h>

// GCN forward: emb-gather -> GCNConv(64->128) -> ReLU -> GCNConv(128->128) -> ReLU
//              -> global_max_pool -> Linear(128->10)
// N=100000, E=600000, VOCAB=5000, G=2000, C=10.
// k_mlp (512 thr / 64 nodes): 16 half-waves x 4 nodes aggregate 64-dim embeddings -> LDS ->
// 8 waves MFMA gemm1(+bias,relu) -> LDS -> MFMA gemm2(dinv scale) -> P. fp16 intermediates.

typedef _Float16 h8 __attribute__((ext_vector_type(8)));
typedef _Float16 h4v __attribute__((ext_vector_type(4)));
typedef float f32x4 __attribute__((ext_vector_type(4)));

// Zero deg (n4i int4s) and pool (p4i int4s).
__global__ __launch_bounds__(256) void k_zero(int4* __restrict__ deg, int n4i,
                                              int4* __restrict__ pool, int p4i) {
    int t = blockIdx.x * 256 + threadIdx.x;
    int4 z = make_int4(0, 0, 0, 0);
    if (t < n4i) deg[t] = z;
    if (t < p4i) pool[t] = z;
}

// Fused: [0,gE) degree atomics; [gE,gE+nCast) e16 = fp16(emb); then W1T; then W2T.
__global__ __launch_bounds__(256) void k_degprep(const int* __restrict__ dst, int* __restrict__ deg, int E,
                                                 const float* __restrict__ emb, __half2* __restrict__ e16,
                                                 const float* __restrict__ W1, _Float16* __restrict__ W1T,
                                                 const float* __restrict__ W2, _Float16* __restrict__ W2T,
                                                 int nEmbF, int gE, int nCast) {
    int bid = blockIdx.x;
    if (bid < gE) {
        int e = bid * 256 + threadIdx.x;
        if (e < E) atomicAdd(&deg[dst[e]], 1);
    } else if (bid < gE + nCast) {
        int t = (bid - gE) * 256 + threadIdx.x;  // one thread = 4 floats
        if (t * 4 < nEmbF) {
            float4 v = *(const float4*)&emb[t * 4];
            e16[t * 2] = __floats2half2_rn(v.x, v.y);
            e16[t * 2 + 1] = __floats2half2_rn(v.z, v.w);
        }
    } else if (bid < gE + nCast + 32) {
        int t = (bid - gE - nCast) * 256 + threadIdx.x;  // 128*64
        int c = t >> 6, k = t & 63;
        W1T[c * 64 + k] = (_Float16)W1[k * 128 + c];
    } else {
        int t = (bid - gE - nCast - 32) * 256 + threadIdx.x;  // 128*128
        if (t < 128 * 128) {
            int c = t >> 7, k = t & 127;
            W2T[c * 128 + k] = (_Float16)W2[k * 128 + c];
        }
    }
}

// scan1 + dinv fused
__global__ __launch_bounds__(256) void k_scan1(const int* __restrict__ deg, int* __restrict__ exc,
                                               int* __restrict__ bsums, float* __restrict__ dinv, int N) {
    __shared__ int s[256];
    int i = blockIdx.x * 256 + threadIdx.x;
    int v = (i < N) ? deg[i] : 0;
    if (i < N) dinv[i] = rsqrtf((float)(v + 1));  // +1 self-loop
    s[threadIdx.x] = v;
    __syncthreads();
    for (int off = 1; off < 256; off <<= 1) {
        int t = (threadIdx.x >= (unsigned)off) ? s[threadIdx.x - off] : 0;
        __syncthreads();
        s[threadIdx.x] += t;
        __syncthreads();
    }
    if (i < N) exc[i] = s[threadIdx.x] - v;
    if (threadIdx.x == 255) bsums[blockIdx.x] = s[255];
}

__global__ __launch_bounds__(512) void k_scan2(int* __restrict__ bsums, int nb) {
    __shared__ int s[512];
    int i = threadIdx.x;
    int v = (i < nb) ? bsums[i] : 0;
    s[i] = v;
    __syncthreads();
    for (int off = 1; off < 512; off <<= 1) {
        int t = (i >= off) ? s[i - off] : 0;
        __syncthreads();
        s[i] += t;
        __syncthreads();
    }
    if (i < nb) bsums[i] = s[i] - v;
}

__global__ __launch_bounds__(256) void k_scan3(int* __restrict__ rowstart, int* __restrict__ cursor,
                                               const int* __restrict__ bsums, int N, int E) {
    int i = blockIdx.x * 256 + threadIdx.x;
    if (i < N) {
        int r = rowstart[i] + bsums[blockIdx.x];
        rowstart[i] = r;
        cursor[i] = r;
    }
    if (i == 0 && blockIdx.x == 0) rowstart[N] = E;
}

// CSR fill: ed[pos] = {x[src], dinv[src] bits}; cols[pos] = src
__global__ __launch_bounds__(256) void k_fill(const int* __restrict__ src, const int* __restrict__ dst,
                                              const int* __restrict__ x, const float* __restrict__ dinv,
                                              int* __restrict__ cursor, int2* __restrict__ ed,
                                              int* __restrict__ cols, int E) {
    int e = blockIdx.x * 256 + threadIdx.x;
    if (e < E) {
        int d = dst[e];
        int s = src[e];
        int pos = atomicAdd(&cursor[d], 1);
        ed[pos] = make_int2(x[s], __float_as_int(dinv[s]));
        cols[pos] = s;
    }
}

// Fused node pipeline: 512 threads, block = 64 nodes.
// Phase 1: Xs[nl] = di*(di*e16[x_i] + sum_j dj*e16[x_j])  (16 half-waves x 4 nodes, 2 passes)
// Phase 2: Hs = relu(Xs @ W1 + b1)   (8 waves: 4 row-blocks x 2 col-halves, MFMA)
// Phase 3: P  = dinv * (Hs @ W2)     (same partition, MFMA)
__global__ __launch_bounds__(512) void k_mlp(const __half2* __restrict__ e16, const int* __restrict__ x,
                                             const float* __restrict__ dinv, const int* __restrict__ rs,
                                             const int2* __restrict__ ed, const _Float16* __restrict__ W1T,
                                             const float* __restrict__ b1, const _Float16* __restrict__ W2T,
                                             _Float16* __restrict__ P, int N) {
    __shared__ _Float16 Xs[64][72];    // 64-dim rows, stride 144B
    __shared__ _Float16 Hs[64][136];   // 128-dim rows, stride 272B
    int tid = threadIdx.x;
    int blk0 = blockIdx.x * 64;
    // ---- Phase 1: embedding-space aggregation ----
    {
        int lane = tid & 31;
        int hw = tid >> 5;  // 0..15
#pragma unroll
        for (int pass = 0; pass < 2; ++pass) {
            int nl = hw * 4 + pass * 2;
            int gA = blk0 + nl;     if (gA >= N) gA = N - 1;
            int gB = blk0 + nl + 1; if (gB >= N) gB = N - 1;
            int cA0 = rs[gA], cA1 = rs[gA + 1];
            int cB0 = rs[gB], cB1 = rs[gB + 1];
            bool hasA = cA0 < cA1, hasB = cB0 < cB1;
            __half2 tA[8], tB[8];
            float wA[8], wB[8];
#pragma unroll
            for (int i = 0; i < 8; ++i) {
                int ei = cA0 + i;
                int ec = (ei < cA1) ? ei : (hasA ? cA1 - 1 : 0);
                int2 r2 = ed[ec];
                tA[i] = e16[(size_t)r2.x * 32 + lane];
                wA[i] = (ei < cA1) ? __int_as_float(r2.y) : 0.f;
            }
#pragma unroll
            for (int i = 0; i < 8; ++i) {
                int ei = cB0 + i;
                int ec = (ei < cB1) ? ei : (hasB ? cB1 - 1 : 0);
                int2 r2 = ed[ec];
                tB[i] = e16[(size_t)r2.x * 32 + lane];
                wB[i] = (ei < cB1) ? __int_as_float(r2.y) : 0.f;
            }
            float dA = dinv[gA], dB = dinv[gB];
            float2 sA = __half22float2(e16[(size_t)x[gA] * 32 + lane]);
            float2 sB = __half22float2(e16[(size_t)x[gB] * 32 + lane]);
            float aA0 = dA * sA.x, aA1 = dA * sA.y;
            float aB0 = dB * sB.x, aB1 = dB * sB.y;
#pragma unroll
            for (int i = 0; i < 8; ++i) {
                float2 tf = __half22float2(tA[i]);
                aA0 = fmaf(wA[i], tf.x, aA0);
                aA1 = fmaf(wA[i], tf.y, aA1);
            }
#pragma unroll
            for (int i = 0; i < 8; ++i) {
                float2 tf = __half22float2(tB[i]);
                aB0 = fmaf(wB[i], tf.x, aB0);
                aB1 = fmaf(wB[i], tf.y, aB1);
            }
            for (int e = cA0 + 8; e < cA1; e += 8) {
#pragma unroll
                for (int i = 0; i < 8; ++i) {
                    int ei = e + i;
                    int ec = (ei < cA1) ? ei : cA1 - 1;
                    int2 r2 = ed[ec];
                    tA[i] = e16[(size_t)r2.x * 32 + lane];
                    wA[i] = (ei < cA1) ? __int_as_float(r2.y) : 0.f;
                }
#pragma unroll
                for (int i = 0; i < 8; ++i) {
                    float2 tf = __half22float2(tA[i]);
                    aA0 = fmaf(wA[i], tf.x, aA0);
                    aA1 = fmaf(wA[i], tf.y, aA1);
                }
            }
            for (int e = cB0 + 8; e < cB1; e += 8) {
#pragma unroll
                for (int i = 0; i < 8; ++i) {
                    int ei = e + i;
                    int ec = (ei < cB1) ? ei : cB1 - 1;
                    int2 r2 = ed[ec];
                    tB[i] = e16[(size_t)r2.x * 32 + lane];
                    wB[i] = (ei < cB1) ? __int_as_float(r2.y) : 0.f;
                }
#pragma unroll
                for (int i = 0; i < 8; ++i) {
                    float2 tf = __half22float2(tB[i]);
                    aB0 = fmaf(wB[i], tf.x, aB0);
                    aB1 = fmaf(wB[i], tf.y, aB1);
                }
            }
            *(__half2*)&Xs[nl][lane * 2] = __floats2half2_rn(dA * aA0, dA * aA1);
            *(__half2*)&Xs[nl + 1][lane * 2] = __floats2half2_rn(dB * aB0, dB * aB1);
        }
    }
    __syncthreads();
    int l = tid & 63, wid = tid >> 6;    // 8 waves
    int r = l & 15, kg = l >> 4;
    int rb = wid & 3;                    // row block: 16 rows
    int ch = wid >> 2;                   // col half: 64 cols
    // ---- Phase 2: Hs = relu(Xs @ W1 + b1), wave = 16 rows x 64 cols ----
    {
        f32x4 acc[4];
#pragma unroll
        for (int ct = 0; ct < 4; ++ct) acc[ct] = (f32x4){0.f, 0.f, 0.f, 0.f};
#pragma unroll
        for (int kc = 0; kc < 2; ++kc) {
            h8 a = *(const h8*)&Xs[rb * 16 + r][kc * 32 + kg * 8];
#pragma unroll
            for (int ct = 0; ct < 4; ++ct) {
                h8 b = *(const h8*)(W1T + (size_t)(ch * 64 + ct * 16 + r) * 64 + kc * 32 + kg * 8);
                acc[ct] = __builtin_amdgcn_mfma_f32_16x16x32_f16(a, b, acc[ct], 0, 0, 0);
            }
        }
#pragma unroll
        for (int ct = 0; ct < 4; ++ct) {
            float bias = b1[ch * 64 + ct * 16 + r];
#pragma unroll
            for (int i = 0; i < 4; ++i)
                Hs[rb * 16 + 4 * kg + i][ch * 64 + ct * 16 + r] =
                    (_Float16)fmaxf(acc[ct][i] + bias, 0.f);
        }
    }
    __syncthreads();
    // ---- Phase 3: P = dinv * (Hs @ W2), wave = 16 rows x 64 cols ----
    {
        f32x4 acc[4];
#pragma unroll
        for (int ct = 0; ct < 4; ++ct) acc[ct] = (f32x4){0.f, 0.f, 0.f, 0.f};
#pragma unroll
        for (int kc = 0; kc < 4; ++kc) {
            h8 a = *(const h8*)&Hs[rb * 16 + r][kc * 32 + kg * 8];
#pragma unroll
            for (int ct = 0; ct < 4; ++ct) {
                h8 b = *(const h8*)(W2T + (size_t)(ch * 64 + ct * 16 + r) * 128 + kc * 32 + kg * 8);
                acc[ct] = __builtin_amdgcn_mfma_f32_16x16x32_f16(a, b, acc[ct], 0, 0, 0);
            }
        }
        float dv[4];
#pragma unroll
        for (int i = 0; i < 4; ++i) {
            int gr = blk0 + rb * 16 + 4 * kg + i;
            dv[i] = (gr < N) ? dinv[gr] : 0.f;
        }
#pragma unroll
        for (int ct = 0; ct < 4; ++ct) {
#pragma unroll
            for (int i = 0; i < 4; ++i) {
                int gr = blk0 + rb * 16 + 4 * kg + i;
                if (gr < N)
                    P[(size_t)gr * 128 + ch * 64 + ct * 16 + r] = (_Float16)(acc[ct][i] * dv[i]);
            }
        }
    }
}

// Layer-2 + global_max_pool. 256-thr block = 8 half-waves x 2 nodes = 16 sorted nodes.
// 16-deep dual-interleaved clamped gathers. LDS pool slots, one global emit per
// (block, graph, feature).
__global__ __launch_bounds__(256) void k_agg2pool(const h4v* __restrict__ P4, const int* __restrict__ batch,
                                                  const float* __restrict__ dinv, const int* __restrict__ rs,
                                                  const int* __restrict__ cols, const float4* __restrict__ bias4,
                                                  float* __restrict__ pool, int N, int G) {
    __shared__ int lpool[4][128];
    int tid = threadIdx.x;
    lpool[tid >> 7][tid & 127] = 0;
    lpool[(tid >> 7) + 2][tid & 127] = 0;
    __syncthreads();
    int lane = tid & 31;
    int blk_n0 = blockIdx.x * 16;
    int gfirst = batch[(blk_n0 < N) ? blk_n0 : (N - 1)];
    int n0 = blk_n0 + (tid >> 5) * 2;
    if (n0 < N) {
        int nA = n0;
        int nB = (n0 + 1 < N) ? n0 + 1 : n0;
        int cA0 = rs[nA], cA1 = rs[nA + 1];
        int cB0 = rs[nB], cB1 = rs[nB + 1];
        bool hasA = cA0 < cA1, hasB = cB0 < cB1;
        h4v sA = P4[(size_t)nA * 32 + lane];
        h4v sB = P4[(size_t)nB * 32 + lane];
        float aA[4], aB[4];
#pragma unroll
        for (int f = 0; f < 4; ++f) {
            aA[f] = (float)sA[f];
            aB[f] = (float)sB[f];
        }
        {
            h4v tA[16], tB[16];
#pragma unroll
            for (int i = 0; i < 16; ++i) {
                int ei = cA0 + i;
                int ec = (ei < cA1) ? ei : (hasA ? cA1 - 1 : 0);
                tA[i] = P4[(size_t)cols[ec] * 32 + lane];
            }
#pragma unroll
            for (int i = 0; i < 16; ++i) {
                int ei = cB0 + i;
                int ec = (ei < cB1) ? ei : (hasB ? cB1 - 1 : 0);
                tB[i] = P4[(size_t)cols[ec] * 32 + lane];
            }
#pragma unroll
            for (int i = 0; i < 16; ++i) {
                float w = (cA0 + i < cA1) ? 1.f : 0.f;
#pragma unroll
                for (int f = 0; f < 4; ++f) aA[f] = fmaf(w, (float)tA[i][f], aA[f]);
            }
#pragma unroll
            for (int i = 0; i < 16; ++i) {
                float w = (cB0 + i < cB1) ? 1.f : 0.f;
#pragma unroll
                for (int f = 0; f < 4; ++f) aB[f] = fmaf(w, (float)tB[i][f], aB[f]);
            }
        }
        for (int e = cA0 + 16; e < cA1; e += 16) {
            h4v t[16];
#pragma unroll
            for (int i = 0; i < 16; ++i) {
                int ei = e + i;
                int ec = (ei < cA1) ? ei : cA1 - 1;
                t[i] = P4[(size_t)cols[ec] * 32 + lane];
            }
#pragma unroll
            for (int i = 0; i < 16; ++i) {
                float w = (e + i < cA1) ? 1.f : 0.f;
#pragma unroll
                for (int f = 0; f < 4; ++f) aA[f] = fmaf(w, (float)t[i][f], aA[f]);
            }
        }
        for (int e = cB0 + 16; e < cB1; e += 16) {
            h4v t[16];
#pragma unroll
            for (int i = 0; i < 16; ++i) {
                int ei = e + i;
                int ec = (ei < cB1) ? ei : cB1 - 1;
                t[i] = P4[(size_t)cols[ec] * 32 + lane];
            }
#pragma unroll
            for (int i = 0; i < 16; ++i) {
                float w = (e + i < cB1) ? 1.f : 0.f;
#pragma unroll
                for (int f = 0; f < 4; ++f) aB[f] = fmaf(w, (float)t[i][f], aB[f]);
            }
        }
        float dA = dinv[nA], dB = dinv[nB];
        int gA = batch[nA], gB = batch[nB];
        float4 b = bias4[lane];
        float bv[4] = {b.x, b.y, b.z, b.w};
        float zA[4], zB[4];
#pragma unroll
        for (int f = 0; f < 4; ++f) {
            zA[f] = fmaxf(fmaf(dA, aA[f], bv[f]), 0.f);
            zB[f] = fmaxf(fmaf(dB, aB[f], bv[f]), 0.f);
        }
        int rot = (lane >> 3) & 3;  // bank-rotation for LDS atomics
        auto emit = [&](int g, const float* m) {
            int slot = g - gfirst;
            if (slot < 4) {
#pragma unroll
                for (int f = 0; f < 4; ++f) {
                    int ff = (f + rot) & 3;
                    if (m[ff] > 0.f) atomicMax(&lpool[slot][lane * 4 + ff], __float_as_int(m[ff]));
                }
            } else {
                float* pg = pool + (size_t)g * 128 + lane * 4;
#pragma unroll
                for (int f = 0; f < 4; ++f)
                    if (m[f] > 0.f) atomicMax((int*)(pg + f), __float_as_int(m[f]));
            }
        };
        if (gA == gB) {
            float m[4];
#pragma unroll
            for (int f = 0; f < 4; ++f) m[f] = fmaxf(zA[f], zB[f]);
            emit(gA, m);
        } else {
            emit(gA, zA);
            emit(gB, zB);
        }
    }
    __syncthreads();
    {
        int f = tid & 127;
        for (int s = tid >> 7; s < 4; s += 2) {
            int v = lpool[s][f];
            if (v > 0) atomicMax((int*)&pool[(size_t)(gfirst + s) * 128 + f], v);
        }
    }
}

// out[g][c] = blin[c] + sum_f pool[g][f] * Wlin[f][c]
__global__ __launch_bounds__(256) void k_final(const float* __restrict__ pool, const float* __restrict__ Wlin,
                                               const float* __restrict__ blin, float* __restrict__ out, int G) {
    int t = blockIdx.x * 256 + threadIdx.x;
    if (t >= G * 10) return;
    int g = t / 10, c = t % 10;
    float acc = blin[c];
    const float* pr = pool + (size_t)g * 128;
#pragma unroll 8
    for (int f = 0; f < 128; ++f) acc = fmaf(pr[f], Wlin[f * 10 + c], acc);
    out[t] = acc;
}

extern "C" void kernel_launch(void* const* d_in, const int* in_sizes, int n_in,
                              void* d_out, int out_size, void* d_ws, size_t ws_size,
                              hipStream_t stream) {
    const int* x = (const int*)d_in[0];
    const int* ei = (const int*)d_in[1];
    const int* batch = (const int*)d_in[2];
    const float* emb = (const float*)d_in[4];
    const float* W1 = (const float*)d_in[5];
    const float* b1 = (const float*)d_in[6];
    const float* W2 = (const float*)d_in[7];
    const float* b2 = (const float*)d_in[8];
    const float* Wlin = (const float*)d_in[9];
    const float* blin = (const float*)d_in[10];
    float* out = (float*)d_out;

    int N = in_sizes[0];
    int E = in_sizes[1] / 2;
    int VOCAB = in_sizes[4] / 64;
    int G = out_size / 10;
    const int* srcp = ei;
    const int* dstp = ei + E;

    char* p = (char*)d_ws;
    auto alloc = [&](size_t bytes) -> char* {
        char* r = p;
        p += (bytes + 255) & ~(size_t)255;
        return r;
    };
    int* deg = (int*)alloc((size_t)N * 4);
    int* cursor = (int*)alloc((size_t)N * 4);
    int* rowstart = (int*)alloc((size_t)(N + 1) * 4);
    int* bsums = (int*)alloc(512 * 4);
    float* dinv = (float*)alloc((size_t)N * 4);
    int2* ed = (int2*)alloc((size_t)E * 8);
    int* cols = (int*)alloc((size_t)E * 4);
    _Float16* e16 = (_Float16*)alloc((size_t)VOCAB * 64 * 2);
    _Float16* W1T = (_Float16*)alloc(128 * 64 * 2);
    _Float16* W2T = (_Float16*)alloc(128 * 128 * 2);
    _Float16* P = (_Float16*)alloc((size_t)N * 128 * 2);
    float* pool = (float*)alloc((size_t)G * 128 * 4);

    int gE = (E + 255) / 256;
    int gN = (N + 255) / 256;  // 391 <= 512 (scan2 capacity)
    int nEmbF = VOCAB * 64;
    int nCast = (nEmbF / 4 + 255) / 256;

    int n4i = N / 4, p4i = G * 128 / 4;
    int zg = ((n4i > p4i ? n4i : p4i) + 255) / 256;
    k_zero<<<zg, 256, 0, stream>>>((int4*)deg, n4i, (int4*)pool, p4i);
    k_degprep<<<gE + nCast + 32 + 64, 256, 0, stream>>>(dstp, deg, E, emb, (__half2*)e16, W1, W1T,
                                                        W2, W2T, nEmbF, gE, nCast);
    k_scan1<<<gN, 256, 0, stream>>>(deg, rowstart, bsums, dinv, N);
    k_scan2<<<1, 512, 0, stream>>>(bsums, gN);
    k_scan3<<<gN, 256, 0, stream>>>(rowstart, cursor, bsums, N, E);
    k_fill<<<gE, 256, 0, stream>>>(srcp, dstp, x, dinv, cursor, ed, cols, E);
    k_mlp<<<(N + 63) / 64, 512, 0, stream>>>((const __half2*)e16, x, dinv, rowstart, ed, W1T, b1,
                                             W2T, P, N);
    k_agg2pool<<<(N + 15) / 16, 256, 0, stream>>>((const h4v*)P, batch, dinv, rowstart, cols,
                                                  (const float4*)b2, pool, N, G);
    k_final<<<(G * 10 + 255) / 256, 256, 0, stream>>>(pool, Wlin, blin, out, G);
}